// Round 1
// baseline (35772.052 us; speedup 1.0000x reference)
//
#include <hip/hip_runtime.h>

#define TSTEPS 512
#define BATCH  64
#define FEAT   512
#define HID    1024
#define NWG    256
#define NTHR   256

typedef _Float16 half8_t  __attribute__((ext_vector_type(8)));
typedef _Float16 half4_t  __attribute__((ext_vector_type(4)));
typedef float    float4_t __attribute__((ext_vector_type(4)));

struct GridBar { unsigned cnt; unsigned gen; };

__device__ __forceinline__ float sigf(float x)      { return 1.0f / (1.0f + __expf(-x)); }
__device__ __forceinline__ float tanh_fast(float x) { return 2.0f / (1.0f + __expf(-2.0f * x)) - 1.0f; }

// x[b][t][f] fp32 -> xT[t][b][f] fp16
__global__ void xpose_kernel(const float* __restrict__ x, _Float16* __restrict__ xT) {
    int idx = blockIdx.x * NTHR + threadIdx.x;   // over B*T*F/4
    int f4 = idx & 127;                          // F/4 = 128
    int bt = idx >> 7;                           // b*T + t
    int t = bt & (TSTEPS - 1);
    int b = bt >> 9;
    float4_t v = ((const float4_t*)x)[idx];
    half4_t h;
    h.x = (_Float16)v.x; h.y = (_Float16)v.y; h.z = (_Float16)v.z; h.w = (_Float16)v.w;
    *(half4_t*)(xT + (size_t)(t * BATCH + b) * FEAT + f4 * 4) = h;
}

// One barrier per step. __syncthreads drains vmcnt (stores are in our XCD L2);
// __threadfence (agent acq_rel) does the L2 writeback / L1+L2 invalidate for
// cross-XCD visibility.
__device__ __forceinline__ void grid_barrier(GridBar* bar, unsigned target) {
    __syncthreads();
    __threadfence();
    if (threadIdx.x == 0) {
        unsigned old = __hip_atomic_fetch_add(&bar->cnt, 1u, __ATOMIC_ACQ_REL, __HIP_MEMORY_SCOPE_AGENT);
        if (old == NWG - 1) {
            __hip_atomic_store(&bar->cnt, 0u, __ATOMIC_RELAXED, __HIP_MEMORY_SCOPE_AGENT);
            __hip_atomic_store(&bar->gen, target, __ATOMIC_RELEASE, __HIP_MEMORY_SCOPE_AGENT);
        } else {
            while (__hip_atomic_load(&bar->gen, __ATOMIC_ACQUIRE, __HIP_MEMORY_SCOPE_AGENT) != target)
                __builtin_amdgcn_s_sleep(2);
        }
    }
    __syncthreads();
    __threadfence();
}

// Persistent 2-layer LSTM. 256 WGs (1/CU), each owns 4 hidden units for both
// layers; weights fp16 in LDS in [kb][m][8] A-fragment layout (m = 4*unit+gate,
// gate order i,f,g,o so C-layout reg r == gate r for lane-quad q == local unit).
__global__ __launch_bounds__(NTHR, 1) void lstm_persistent(
    const float* __restrict__ Wih0, const float* __restrict__ Whh0,
    const float* __restrict__ bih0, const float* __restrict__ bhh0,
    const float* __restrict__ Wih1, const float* __restrict__ Whh1,
    const float* __restrict__ bih1, const float* __restrict__ bhh1,
    const _Float16* __restrict__ xT,
    _Float16* __restrict__ h0buf,   // [2][64][1024] fp16, double-buffered
    _Float16* __restrict__ h1buf,   // [2][64][1024] fp16
    GridBar* __restrict__ bar,
    float* __restrict__ out)        // out[64][512][1024] | hT[2][64][1024] | cT[2][64][1024]
{
    extern __shared__ __align__(16) char smem[];
    _Float16* w0x = (_Float16*)smem;        // [ 64][16][8]  K=512  (W_ih_0 slice)
    _Float16* w0h = w0x + 16 * FEAT;        // [128][16][8]  K=1024 (W_hh_0 slice)
    _Float16* w1  = w0h + 16 * HID;         // [256][16][8]  K=2048 (W_ih_1 ++ W_hh_1)

    const int wg  = blockIdx.x;
    const int u0  = ((wg & 7) * 32 + (wg >> 3)) * 4;  // XCD-contiguous unit blocks
    const int tid = threadIdx.x;

    // ---- one-time: convert fp32 weight slices -> fp16 LDS fragments ----
    for (int idx = tid; idx < 16 * FEAT; idx += NTHR) {
        int m = idx >> 9, k = idx & (FEAT - 1);
        int grow = (m & 3) * HID + u0 + (m >> 2);
        w0x[(((k >> 3) * 16) + m) * 8 + (k & 7)] = (_Float16)Wih0[grow * FEAT + k];
    }
    for (int idx = tid; idx < 16 * HID; idx += NTHR) {
        int m = idx >> 10, k = idx & (HID - 1);
        int grow = (m & 3) * HID + u0 + (m >> 2);
        w0h[(((k >> 3) * 16) + m) * 8 + (k & 7)] = (_Float16)Whh0[grow * HID + k];
    }
    for (int idx = tid; idx < 16 * 2048; idx += NTHR) {
        int m = idx >> 11, k = idx & 2047;
        int grow = (m & 3) * HID + u0 + (m >> 2);
        float v = (k < HID) ? Wih1[grow * HID + k] : Whh1[grow * HID + (k - HID)];
        w1[(((k >> 3) * 16) + m) * 8 + (k & 7)] = (_Float16)v;
    }

    const int lane  = tid & 63;
    const int wv    = tid >> 6;      // wave -> 16-batch tile
    const int q     = lane >> 4;     // quad: local unit (for C) / k-block (for A,B)
    const int n     = lane & 15;     // col: batch (for C/B) / row m (for A)
    const int batch = wv * 16 + n;
    const int unit  = u0 + q;

    float b0r[4], b1r[4];
#pragma unroll
    for (int r = 0; r < 4; ++r) {
        int grow = r * HID + unit;
        b0r[r] = bih0[grow] + bhh0[grow];
        b1r[r] = bih1[grow] + bhh1[grow];
    }

    __syncthreads();

    const half8_t* a0x = (const half8_t*)w0x;
    const half8_t* a0h = (const half8_t*)w0h;
    const half8_t* a1  = (const half8_t*)w1;
    const float4_t fzero = {0.f, 0.f, 0.f, 0.f};

    float c0 = 0.f, c1 = 0.f, h0v = 0.f, h1v = 0.f;

    for (int t = 0; t < TSTEPS; ++t) {
        const _Float16* h0r = h0buf + (((t & 1) ^ 1) * (BATCH * HID));
        _Float16*       h0w = h0buf + ((t & 1) * (BATCH * HID));
        const _Float16* h1r = h1buf + (((t & 1) ^ 1) * (BATCH * HID));
        _Float16*       h1w = h1buf + ((t & 1) * (BATCH * HID));

        // ---------- layer 0: gates = x_t@Wih0^T + h0@Whh0^T + b ----------
        float4_t acc[4];
        acc[0] = fzero; acc[1] = fzero; acc[2] = fzero; acc[3] = fzero;
        {
            const _Float16* xb = xT + (size_t)(t * BATCH + batch) * FEAT + q * 8;
#pragma unroll 8
            for (int s = 0; s < 16; ++s) {
                half8_t a = a0x[(s * 4 + q) * 16 + n];
                half8_t b = *(const half8_t*)(xb + s * 32);
                acc[s & 3] = __builtin_amdgcn_mfma_f32_16x16x32_f16(a, b, acc[s & 3], 0, 0, 0);
            }
            const _Float16* hb = h0r + batch * HID + q * 8;
#pragma unroll 8
            for (int s = 0; s < 32; ++s) {
                half8_t a = a0h[(s * 4 + q) * 16 + n];
                half8_t b = *(const half8_t*)(hb + s * 32);
                acc[s & 3] = __builtin_amdgcn_mfma_f32_16x16x32_f16(a, b, acc[s & 3], 0, 0, 0);
            }
        }
        {
            float4_t g = (acc[0] + acc[1]) + (acc[2] + acc[3]);
            float I = sigf(g.x + b0r[0]);
            float F = sigf(g.y + b0r[1]);
            float G = tanh_fast(g.z + b0r[2]);
            float O = sigf(g.w + b0r[3]);
            c0  = F * c0 + I * G;
            h0v = O * tanh_fast(c0);
        }
        h0w[batch * HID + unit] = (_Float16)h0v;

        grid_barrier(bar, (unsigned)(t + 1));

        // ---------- layer 1: gates = h0_new@Wih1^T + h1@Whh1^T + b ----------
        acc[0] = fzero; acc[1] = fzero; acc[2] = fzero; acc[3] = fzero;
        {
            const _Float16* p0 = h0w + batch * HID + q * 8;
#pragma unroll 8
            for (int s = 0; s < 32; ++s) {
                half8_t a = a1[(s * 4 + q) * 16 + n];
                half8_t b = *(const half8_t*)(p0 + s * 32);
                acc[s & 3] = __builtin_amdgcn_mfma_f32_16x16x32_f16(a, b, acc[s & 3], 0, 0, 0);
            }
            const _Float16* p1 = h1r + batch * HID + q * 8;
#pragma unroll 8
            for (int s = 0; s < 32; ++s) {
                half8_t a = a1[(128 + s * 4 + q) * 16 + n];
                half8_t b = *(const half8_t*)(p1 + s * 32);
                acc[s & 3] = __builtin_amdgcn_mfma_f32_16x16x32_f16(a, b, acc[s & 3], 0, 0, 0);
            }
        }
        {
            float4_t g = (acc[0] + acc[1]) + (acc[2] + acc[3]);
            float I = sigf(g.x + b1r[0]);
            float F = sigf(g.y + b1r[1]);
            float G = tanh_fast(g.z + b1r[2]);
            float O = sigf(g.w + b1r[3]);
            c1  = F * c1 + I * G;
            h1v = O * tanh_fast(c1);
        }
        h1w[batch * HID + unit] = (_Float16)h1v;
        out[((size_t)batch * TSTEPS + t) * HID + unit] = h1v;
    }

    float* hT = out + (size_t)BATCH * TSTEPS * HID;
    float* cT = hT + 2 * BATCH * HID;
    hT[batch * HID + unit]              = h0v;
    hT[BATCH * HID + batch * HID + unit] = h1v;
    cT[batch * HID + unit]              = c0;
    cT[BATCH * HID + batch * HID + unit] = c1;
}

extern "C" void kernel_launch(void* const* d_in, const int* in_sizes, int n_in,
                              void* d_out, int out_size, void* d_ws, size_t ws_size,
                              hipStream_t stream) {
    (void)in_sizes; (void)n_in; (void)out_size; (void)ws_size;
    const float* x    = (const float*)d_in[0];
    const float* Wih0 = (const float*)d_in[1];
    const float* Whh0 = (const float*)d_in[2];
    const float* bih0 = (const float*)d_in[3];
    const float* bhh0 = (const float*)d_in[4];
    const float* Wih1 = (const float*)d_in[5];
    const float* Whh1 = (const float*)d_in[6];
    const float* bih1 = (const float*)d_in[7];
    const float* bhh1 = (const float*)d_in[8];

    char* ws = (char*)d_ws;
    GridBar*  bar   = (GridBar*)ws;
    _Float16* h0buf = (_Float16*)(ws + 1024);
    _Float16* h1buf = (_Float16*)(ws + 1024 + 2 * BATCH * HID * sizeof(_Float16));
    _Float16* xT    = (_Float16*)(ws + (1 << 20));   // 32 MB region

    // zero barrier state + h/c start buffers (ws is poisoned 0xAA each call)
    hipMemsetAsync(d_ws, 0, 1 << 20, stream);

    xpose_kernel<<<(BATCH * TSTEPS * FEAT / 4) / NTHR, NTHR, 0, stream>>>(x, xT);

    const int shmem = 16 * (FEAT + HID + 2048) * (int)sizeof(_Float16);  // 114688 B
    hipFuncSetAttribute((const void*)lstm_persistent,
                        hipFuncAttributeMaxDynamicSharedMemorySize, shmem);
    lstm_persistent<<<NWG, NTHR, shmem, stream>>>(
        Wih0, Whh0, bih0, bhh0, Wih1, Whh1, bih1, bhh1,
        xT, h0buf, h1buf, bar, (float*)d_out);
}

// Round 2
// 22175.626 us; speedup vs baseline: 1.6131x; 1.6131x over previous
//
#include <hip/hip_runtime.h>

#define TSTEPS 512
#define BATCH  64
#define FEAT   512
#define HID    1024
#define NWG    256
#define NTHR   256

typedef _Float16 half8_t  __attribute__((ext_vector_type(8)));
typedef _Float16 half4_t  __attribute__((ext_vector_type(4)));
typedef float    float4_t __attribute__((ext_vector_type(4)));

__device__ __forceinline__ float sigf(float x)      { return 1.0f / (1.0f + __expf(-x)); }
__device__ __forceinline__ float tanh_fast(float x) { return 2.0f / (1.0f + __expf(-2.0f * x)) - 1.0f; }

// x[b][t][f] fp32 -> xT[t][b][f] fp16
__global__ void xpose_kernel(const float* __restrict__ x, _Float16* __restrict__ xT) {
    int idx = blockIdx.x * NTHR + threadIdx.x;   // over B*T*F/4
    int f4 = idx & 127;                          // F/4 = 128
    int bt = idx >> 7;                           // b*T + t
    int t = bt & (TSTEPS - 1);
    int b = bt >> 9;
    float4_t v = ((const float4_t*)x)[idx];
    half4_t h;
    h.x = (_Float16)v.x; h.y = (_Float16)v.y; h.z = (_Float16)v.z; h.w = (_Float16)v.w;
    *(half4_t*)(xT + (size_t)(t * BATCH + b) * FEAT + f4 * 4) = h;
}

// Two-level grid barrier, monotone counters (no reset).
// bar[0]=gen, bar[32]=root, bar[64+32*x]=line[x]  (128B-spaced, zero-init).
// Release on arrive (one wbl2/WG/step), RELAXED polling (no per-poll inv!),
// one acquire fence per wave on exit.
__device__ __forceinline__ void grid_barrier(unsigned* bar, int line_id, unsigned step) {
    __syncthreads();                       // drains all waves' vmem to L2
    if (threadIdx.x == 0) {
        unsigned* gen  = bar;
        unsigned* root = bar + 32;
        unsigned* line = bar + 64 + 32 * line_id;
        unsigned old = __hip_atomic_fetch_add(line, 1u, __ATOMIC_RELEASE, __HIP_MEMORY_SCOPE_AGENT);
        if (old == 32u * step - 1u) {
            unsigned r = __hip_atomic_fetch_add(root, 1u, __ATOMIC_RELEASE, __HIP_MEMORY_SCOPE_AGENT);
            if (r == 8u * step - 1u)
                __hip_atomic_store(gen, step, __ATOMIC_RELEASE, __HIP_MEMORY_SCOPE_AGENT);
        }
        while (__hip_atomic_load(gen, __ATOMIC_RELAXED, __HIP_MEMORY_SCOPE_AGENT) < step)
            __builtin_amdgcn_s_sleep(1);
    }
    __syncthreads();
    __builtin_amdgcn_fence(__ATOMIC_ACQUIRE, "agent");   // one inv per wave
}

// Persistent 2-layer LSTM. 256 WGs (1/CU, LDS-forced), each owns 4 hidden
// units per layer; weights fp16 in LDS in [kb][m][8] A-fragment layout.
// Step schedule (one grid barrier per step):
//   barrier -> load p0=h0(t) frags (also reused by L0(t+1)!), L1(t),
//   L0(t+1) from p0+xreg, prefetch xreg(t+2), barrier.
__global__ __launch_bounds__(NTHR, 1) void lstm_persistent(
    const float* __restrict__ Wih0, const float* __restrict__ Whh0,
    const float* __restrict__ bih0, const float* __restrict__ bhh0,
    const float* __restrict__ Wih1, const float* __restrict__ Whh1,
    const float* __restrict__ bih1, const float* __restrict__ bhh1,
    const _Float16* __restrict__ xT,
    _Float16* __restrict__ h0buf,   // [2][64][1024] fp16
    _Float16* __restrict__ h1buf,   // [2][64][1024] fp16
    unsigned* __restrict__ bar,
    float* __restrict__ out)        // out[64][512][1024] | hT[2][64][1024] | cT[2][64][1024]
{
    extern __shared__ __align__(16) char smem[];
    _Float16* w0x = (_Float16*)smem;        // [ 64][16][8]  K=512  (W_ih_0 slice)
    _Float16* w0h = w0x + 16 * FEAT;        // [128][16][8]  K=1024 (W_hh_0 slice)
    _Float16* w1  = w0h + 16 * HID;         // [256][16][8]  K=2048 (W_ih_1 ++ W_hh_1)

    const int wg  = blockIdx.x;
    const int u0  = ((wg & 7) * 32 + (wg >> 3)) * 4;  // XCD-contiguous unit blocks
    const int tid = threadIdx.x;

    // ---- one-time: convert fp32 weight slices -> fp16 LDS fragments ----
    for (int idx = tid; idx < 16 * FEAT; idx += NTHR) {
        int m = idx >> 9, k = idx & (FEAT - 1);
        int grow = (m & 3) * HID + u0 + (m >> 2);
        w0x[(((k >> 3) * 16) + m) * 8 + (k & 7)] = (_Float16)Wih0[grow * FEAT + k];
    }
    for (int idx = tid; idx < 16 * HID; idx += NTHR) {
        int m = idx >> 10, k = idx & (HID - 1);
        int grow = (m & 3) * HID + u0 + (m >> 2);
        w0h[(((k >> 3) * 16) + m) * 8 + (k & 7)] = (_Float16)Whh0[grow * HID + k];
    }
    for (int idx = tid; idx < 16 * 2048; idx += NTHR) {
        int m = idx >> 11, k = idx & 2047;
        int grow = (m & 3) * HID + u0 + (m >> 2);
        float v = (k < HID) ? Wih1[grow * HID + k] : Whh1[grow * HID + (k - HID)];
        w1[(((k >> 3) * 16) + m) * 8 + (k & 7)] = (_Float16)v;
    }

    const int lane  = tid & 63;
    const int wv    = tid >> 6;      // wave -> 16-batch tile
    const int q     = lane >> 4;     // quad: local unit (for C) / k-block (for A,B)
    const int n     = lane & 15;     // col: batch (for C/B) / row m (for A)
    const int batch = wv * 16 + n;
    const int unit  = u0 + q;

    float b0r[4], b1r[4];
#pragma unroll
    for (int r = 0; r < 4; ++r) {
        int grow = r * HID + unit;
        b0r[r] = bih0[grow] + bhh0[grow];
        b1r[r] = bih1[grow] + bhh1[grow];
    }

    __syncthreads();

    const half8_t* a0x = (const half8_t*)w0x;
    const half8_t* a0h = (const half8_t*)w0h;
    const half8_t* a1  = (const half8_t*)w1;
    const float4_t fzero = {0.f, 0.f, 0.f, 0.f};

    float c0 = 0.f, c1 = 0.f, h0v = 0.f, h1v = 0.f;
    float4_t acc[4];
    half8_t  xreg[16];

    // ---- prologue: L0(0): gates = x_0 @ Wih0^T + b   (h0_prev = 0) ----
    {
        const _Float16* xb = xT + (size_t)batch * FEAT + q * 8;
        acc[0] = fzero; acc[1] = fzero; acc[2] = fzero; acc[3] = fzero;
#pragma unroll
        for (int s = 0; s < 16; ++s)
            acc[s & 3] = __builtin_amdgcn_mfma_f32_16x16x32_f16(
                a0x[(s * 4 + q) * 16 + n], *(const half8_t*)(xb + s * 32), acc[s & 3], 0, 0, 0);
        float4_t g = (acc[0] + acc[1]) + (acc[2] + acc[3]);
        float I = sigf(g.x + b0r[0]);
        float G = tanh_fast(g.z + b0r[2]);
        float O = sigf(g.w + b0r[3]);
        c0  = I * G;                   // f * c_prev = 0
        h0v = O * tanh_fast(c0);
        h0buf[batch * HID + unit] = (_Float16)h0v;     // buffer 0 = h0(0)
    }
    {   // prefetch x(1)
        const _Float16* xb = xT + ((size_t)BATCH + batch) * FEAT + q * 8;
#pragma unroll
        for (int s = 0; s < 16; ++s) xreg[s] = *(const half8_t*)(xb + s * 32);
    }
    grid_barrier(bar, wg & 7, 1u);

    for (int t = 0; t < TSTEPS; ++t) {
        // ---- p0 = h0(t) fragments: feed L1(t) now, L0(t+1) later ----
        const _Float16* h0cur = h0buf + (t & 1) * (BATCH * HID) + batch * HID + q * 8;
        half8_t p0r[32];
#pragma unroll
        for (int s = 0; s < 32; ++s) p0r[s] = *(const half8_t*)(h0cur + s * 32);

        // ---------- layer 1: gates = h0(t)@Wih1^T + h1(t-1)@Whh1^T + b ----------
        acc[0] = fzero; acc[1] = fzero; acc[2] = fzero; acc[3] = fzero;
#pragma unroll 8
        for (int s = 0; s < 32; ++s)
            acc[s & 3] = __builtin_amdgcn_mfma_f32_16x16x32_f16(
                a1[(s * 4 + q) * 16 + n], p0r[s], acc[s & 3], 0, 0, 0);
        {
            const _Float16* p1 = h1buf + ((t & 1) ^ 1) * (BATCH * HID) + batch * HID + q * 8;
#pragma unroll 8
            for (int s = 0; s < 32; ++s)
                acc[s & 3] = __builtin_amdgcn_mfma_f32_16x16x32_f16(
                    a1[(128 + s * 4 + q) * 16 + n], *(const half8_t*)(p1 + s * 32), acc[s & 3], 0, 0, 0);
        }
        {
            float4_t g = (acc[0] + acc[1]) + (acc[2] + acc[3]);
            float I = sigf(g.x + b1r[0]);
            float F = sigf(g.y + b1r[1]);
            float G = tanh_fast(g.z + b1r[2]);
            float O = sigf(g.w + b1r[3]);
            c1  = F * c1 + I * G;
            h1v = O * tanh_fast(c1);
        }
        h1buf[(t & 1) * (BATCH * HID) + batch * HID + unit] = (_Float16)h1v;
        out[((size_t)batch * TSTEPS + t) * HID + unit] = h1v;

        if (t + 1 < TSTEPS) {
            // prefetch x(t+2) — overlaps with L0 compute + barrier wait
            if (t + 2 < TSTEPS) {
                const _Float16* xb = xT + ((size_t)(t + 2) * BATCH + batch) * FEAT + q * 8;
#pragma unroll
                for (int s = 0; s < 16; ++s) xreg[s] = *(const half8_t*)(xb + s * 32);
            }
            // ---------- layer 0 for t+1: x(t+1)@Wih0^T + h0(t)@Whh0^T + b ----------
            acc[0] = fzero; acc[1] = fzero; acc[2] = fzero; acc[3] = fzero;
#pragma unroll 8
            for (int s = 0; s < 16; ++s)
                acc[s & 3] = __builtin_amdgcn_mfma_f32_16x16x32_f16(
                    a0x[(s * 4 + q) * 16 + n], xreg[s], acc[s & 3], 0, 0, 0);
#pragma unroll 8
            for (int s = 0; s < 32; ++s)
                acc[s & 3] = __builtin_amdgcn_mfma_f32_16x16x32_f16(
                    a0h[(s * 4 + q) * 16 + n], p0r[s], acc[s & 3], 0, 0, 0);
            // NOTE: xreg now holds x(t+2); the MFMA loop above consumed the OLD
            // xreg values? NO — we overwrote them. Must consume before refill.
            // (see corrected ordering below — this branch is never compiled)
            {
                float4_t g = (acc[0] + acc[1]) + (acc[2] + acc[3]);
                float I = sigf(g.x + b0r[0]);
                float F = sigf(g.y + b0r[1]);
                float G = tanh_fast(g.z + b0r[2]);
                float O = sigf(g.w + b0r[3]);
                c0  = F * c0 + I * G;
                h0v = O * tanh_fast(c0);
            }
            h0buf[((t + 1) & 1) * (BATCH * HID) + batch * HID + unit] = (_Float16)h0v;
            grid_barrier(bar, wg & 7, (unsigned)(t + 2));
        }
    }

    float* hT = out + (size_t)BATCH * TSTEPS * HID;
    float* cT = hT + 2 * BATCH * HID;
    hT[batch * HID + unit]               = h0v;
    hT[BATCH * HID + batch * HID + unit] = h1v;
    cT[batch * HID + unit]               = c0;
    cT[BATCH * HID + batch * HID + unit] = c1;
}

// ---- corrected kernel: consume xreg BEFORE refilling it ----
// (The version above has a WAR bug on xreg; this is the real kernel used.)
__global__ __launch_bounds__(NTHR, 1) void lstm_persistent2(
    const float* __restrict__ Wih0, const float* __restrict__ Whh0,
    const float* __restrict__ bih0, const float* __restrict__ bhh0,
    const float* __restrict__ Wih1, const float* __restrict__ Whh1,
    const float* __restrict__ bih1, const float* __restrict__ bhh1,
    const _Float16* __restrict__ xT,
    _Float16* __restrict__ h0buf, _Float16* __restrict__ h1buf,
    unsigned* __restrict__ bar, float* __restrict__ out)
{
    extern __shared__ __align__(16) char smem[];
    _Float16* w0x = (_Float16*)smem;
    _Float16* w0h = w0x + 16 * FEAT;
    _Float16* w1  = w0h + 16 * HID;

    const int wg  = blockIdx.x;
    const int u0  = ((wg & 7) * 32 + (wg >> 3)) * 4;
    const int tid = threadIdx.x;

    for (int idx = tid; idx < 16 * FEAT; idx += NTHR) {
        int m = idx >> 9, k = idx & (FEAT - 1);
        int grow = (m & 3) * HID + u0 + (m >> 2);
        w0x[(((k >> 3) * 16) + m) * 8 + (k & 7)] = (_Float16)Wih0[grow * FEAT + k];
    }
    for (int idx = tid; idx < 16 * HID; idx += NTHR) {
        int m = idx >> 10, k = idx & (HID - 1);
        int grow = (m & 3) * HID + u0 + (m >> 2);
        w0h[(((k >> 3) * 16) + m) * 8 + (k & 7)] = (_Float16)Whh0[grow * HID + k];
    }
    for (int idx = tid; idx < 16 * 2048; idx += NTHR) {
        int m = idx >> 11, k = idx & 2047;
        int grow = (m & 3) * HID + u0 + (m >> 2);
        float v = (k < HID) ? Wih1[grow * HID + k] : Whh1[grow * HID + (k - HID)];
        w1[(((k >> 3) * 16) + m) * 8 + (k & 7)] = (_Float16)v;
    }

    const int lane  = tid & 63;
    const int wv    = tid >> 6;
    const int q     = lane >> 4;
    const int n     = lane & 15;
    const int batch = wv * 16 + n;
    const int unit  = u0 + q;

    float b0r[4], b1r[4];
#pragma unroll
    for (int r = 0; r < 4; ++r) {
        int grow = r * HID + unit;
        b0r[r] = bih0[grow] + bhh0[grow];
        b1r[r] = bih1[grow] + bhh1[grow];
    }

    __syncthreads();

    const half8_t* a0x = (const half8_t*)w0x;
    const half8_t* a0h = (const half8_t*)w0h;
    const half8_t* a1  = (const half8_t*)w1;
    const float4_t fzero = {0.f, 0.f, 0.f, 0.f};

    float c0 = 0.f, c1 = 0.f, h0v = 0.f, h1v = 0.f;
    float4_t acc[4];
    half8_t  xreg[16];

    // prologue: L0(0) with h0_prev = 0
    {
        const _Float16* xb = xT + (size_t)batch * FEAT + q * 8;
        acc[0] = fzero; acc[1] = fzero; acc[2] = fzero; acc[3] = fzero;
#pragma unroll
        for (int s = 0; s < 16; ++s)
            acc[s & 3] = __builtin_amdgcn_mfma_f32_16x16x32_f16(
                a0x[(s * 4 + q) * 16 + n], *(const half8_t*)(xb + s * 32), acc[s & 3], 0, 0, 0);
        float4_t g = (acc[0] + acc[1]) + (acc[2] + acc[3]);
        float I = sigf(g.x + b0r[0]);
        float G = tanh_fast(g.z + b0r[2]);
        float O = sigf(g.w + b0r[3]);
        c0  = I * G;
        h0v = O * tanh_fast(c0);
        h0buf[batch * HID + unit] = (_Float16)h0v;
    }
    {
        const _Float16* xb = xT + ((size_t)BATCH + batch) * FEAT + q * 8;
#pragma unroll
        for (int s = 0; s < 16; ++s) xreg[s] = *(const half8_t*)(xb + s * 32);
    }
    grid_barrier(bar, wg & 7, 1u);

    for (int t = 0; t < TSTEPS; ++t) {
        const _Float16* h0cur = h0buf + (t & 1) * (BATCH * HID) + batch * HID + q * 8;
        half8_t p0r[32];
#pragma unroll
        for (int s = 0; s < 32; ++s) p0r[s] = *(const half8_t*)(h0cur + s * 32);

        // layer 1 at t
        acc[0] = fzero; acc[1] = fzero; acc[2] = fzero; acc[3] = fzero;
#pragma unroll 8
        for (int s = 0; s < 32; ++s)
            acc[s & 3] = __builtin_amdgcn_mfma_f32_16x16x32_f16(
                a1[(s * 4 + q) * 16 + n], p0r[s], acc[s & 3], 0, 0, 0);
        {
            const _Float16* p1 = h1buf + ((t & 1) ^ 1) * (BATCH * HID) + batch * HID + q * 8;
#pragma unroll 8
            for (int s = 0; s < 32; ++s)
                acc[s & 3] = __builtin_amdgcn_mfma_f32_16x16x32_f16(
                    a1[(128 + s * 4 + q) * 16 + n], *(const half8_t*)(p1 + s * 32), acc[s & 3], 0, 0, 0);
        }
        {
            float4_t g = (acc[0] + acc[1]) + (acc[2] + acc[3]);
            float I = sigf(g.x + b1r[0]);
            float F = sigf(g.y + b1r[1]);
            float G = tanh_fast(g.z + b1r[2]);
            float O = sigf(g.w + b1r[3]);
            c1  = F * c1 + I * G;
            h1v = O * tanh_fast(c1);
        }
        h1buf[(t & 1) * (BATCH * HID) + batch * HID + unit] = (_Float16)h1v;
        out[((size_t)batch * TSTEPS + t) * HID + unit] = h1v;

        if (t + 1 < TSTEPS) {
            // layer 0 at t+1 — consumes xreg (holds x(t+1)) and p0r (h0(t))
            acc[0] = fzero; acc[1] = fzero; acc[2] = fzero; acc[3] = fzero;
#pragma unroll 8
            for (int s = 0; s < 16; ++s)
                acc[s & 3] = __builtin_amdgcn_mfma_f32_16x16x32_f16(
                    a0x[(s * 4 + q) * 16 + n], xreg[s], acc[s & 3], 0, 0, 0);
#pragma unroll 8
            for (int s = 0; s < 32; ++s)
                acc[s & 3] = __builtin_amdgcn_mfma_f32_16x16x32_f16(
                    a0h[(s * 4 + q) * 16 + n], p0r[s], acc[s & 3], 0, 0, 0);
            {
                float4_t g = (acc[0] + acc[1]) + (acc[2] + acc[3]);
                float I = sigf(g.x + b0r[0]);
                float F = sigf(g.y + b0r[1]);
                float G = tanh_fast(g.z + b0r[2]);
                float O = sigf(g.w + b0r[3]);
                c0  = F * c0 + I * G;
                h0v = O * tanh_fast(c0);
            }
            h0buf[((t + 1) & 1) * (BATCH * HID) + batch * HID + unit] = (_Float16)h0v;
            // refill xreg with x(t+2) AFTER consumption; overlaps barrier wait
            if (t + 2 < TSTEPS) {
                const _Float16* xb = xT + ((size_t)(t + 2) * BATCH + batch) * FEAT + q * 8;
#pragma unroll
                for (int s = 0; s < 16; ++s) xreg[s] = *(const half8_t*)(xb + s * 32);
            }
            grid_barrier(bar, wg & 7, (unsigned)(t + 2));
        }
    }

    float* hT = out + (size_t)BATCH * TSTEPS * HID;
    float* cT = hT + 2 * BATCH * HID;
    hT[batch * HID + unit]               = h0v;
    hT[BATCH * HID + batch * HID + unit] = h1v;
    cT[batch * HID + unit]               = c0;
    cT[BATCH * HID + batch * HID + unit] = c1;
}

extern "C" void kernel_launch(void* const* d_in, const int* in_sizes, int n_in,
                              void* d_out, int out_size, void* d_ws, size_t ws_size,
                              hipStream_t stream) {
    (void)in_sizes; (void)n_in; (void)out_size; (void)ws_size;
    const float* x    = (const float*)d_in[0];
    const float* Wih0 = (const float*)d_in[1];
    const float* Whh0 = (const float*)d_in[2];
    const float* bih0 = (const float*)d_in[3];
    const float* bhh0 = (const float*)d_in[4];
    const float* Wih1 = (const float*)d_in[5];
    const float* Whh1 = (const float*)d_in[6];
    const float* bih1 = (const float*)d_in[7];
    const float* bhh1 = (const float*)d_in[8];

    char* ws = (char*)d_ws;
    unsigned* bar   = (unsigned*)ws;                 // 2KB barrier area
    _Float16* h0buf = (_Float16*)(ws + 4096);
    _Float16* h1buf = (_Float16*)(ws + 4096 + 2 * BATCH * HID * sizeof(_Float16));
    _Float16* xT    = (_Float16*)(ws + (1 << 20));   // 32 MB region

    hipMemsetAsync(d_ws, 0, 1 << 20, stream);        // zero barrier + h bufs

    xpose_kernel<<<(BATCH * TSTEPS * FEAT / 4) / NTHR, NTHR, 0, stream>>>(x, xT);

    const int shmem = 16 * (FEAT + HID + 2048) * (int)sizeof(_Float16);  // 114688 B
    hipFuncSetAttribute((const void*)lstm_persistent2,
                        hipFuncAttributeMaxDynamicSharedMemorySize, shmem);
    lstm_persistent2<<<NWG, NTHR, shmem, stream>>>(
        Wih0, Whh0, bih0, bhh0, Wih1, Whh1, bih1, bhh1,
        xT, h0buf, h1buf, bar, (float*)d_out);
}